// Round 15
// baseline (1062.572 us; speedup 1.0000x reference)
//
#include <hip/hip_runtime.h>
#include <hip/hip_bf16.h>
#include <math.h>

// Problem constants
#define BB    16
#define LS    256
#define LT    128
#define EMB   128
#define HID   256
#define G4    1024      // 4*HID
#define VOCAB 32000

// LSTM slicing: 8 slice-WGs per batch, 512 threads each. (R10/R14-proven)
#define NSL   8
#define XROWS 112      // LDS-staged xz steps per burst (56 KB)
#define LSTM_POOL (4096 + 1024 + XROWS * 128 * 4)   // part + hbuf + xbuf = 62464 B

typedef __attribute__((ext_vector_type(8))) short bf16x8;
typedef __attribute__((ext_vector_type(4))) float f32x4;
typedef __attribute__((ext_vector_type(4))) int   i32x4;
typedef unsigned short ushort_t;
typedef unsigned int uint_t;

__device__ inline float sigf(float x)      { return 1.0f / (1.0f + __expf(-x)); }
__device__ inline float tanhfast(float x)  { return 1.0f - 2.0f / (1.0f + __expf(2.0f * x)); }
__device__ inline ushort_t bf16_rne(float f) {
  __hip_bfloat16 h = __float2bfloat16(f);
  return *(ushort_t*)&h;
}

// ---------------------------------------------------------------------------
// Kernel 1: xz = emb[idx] @ Wk + b for BOTH enc and dec (one launch).
// ---------------------------------------------------------------------------
__global__ __launch_bounds__(256) void embed_proj_kernel(
    const int* __restrict__ x, const int* __restrict__ y,
    const float* __restrict__ eemb, const float* __restrict__ eWk,
    const float* __restrict__ eb,
    const float* __restrict__ demb, const float* __restrict__ dWk,
    const float* __restrict__ db,
    float* __restrict__ xze, float* __restrict__ xzd)
{
  const bool enc = blockIdx.x < 128;
  const int* idx = enc ? x : y;
  const float* emb = enc ? eemb : demb;
  const float* Wk  = enc ? eWk  : dWk;
  const float* bias= enc ? eb   : db;
  float* xz        = enc ? xze  : xzd;
  const int row0 = (enc ? blockIdx.x : blockIdx.x - 128) * 32;

  __shared__ float e[32][EMB];    // 16 KB
  const int tid = threadIdx.x;

  for (int i = tid; i < 32 * EMB; i += 256) {
    int r = i >> 7, k = i & 127;
    int token = idx[row0 + r];
    e[r][k] = emb[(size_t)token * EMB + k];
  }
  __syncthreads();

  float acc[4][32];
#pragma unroll
  for (int q = 0; q < 4; ++q)
#pragma unroll
    for (int r = 0; r < 32; ++r) acc[q][r] = 0.0f;

  for (int k = 0; k < EMB; ++k) {
    float w0 = Wk[(size_t)k * G4 + 0 * 256 + tid];
    float w1 = Wk[(size_t)k * G4 + 1 * 256 + tid];
    float w2 = Wk[(size_t)k * G4 + 2 * 256 + tid];
    float w3 = Wk[(size_t)k * G4 + 3 * 256 + tid];
#pragma unroll
    for (int r = 0; r < 32; ++r) {
      float ev = e[r][k];
      acc[0][r] = fmaf(ev, w0, acc[0][r]);
      acc[1][r] = fmaf(ev, w1, acc[1][r]);
      acc[2][r] = fmaf(ev, w2, acc[2][r]);
      acc[3][r] = fmaf(ev, w3, acc[3][r]);
    }
  }
#pragma unroll
  for (int q = 0; q < 4; ++q) {
    float bb = bias[q * 256 + tid];
#pragma unroll
    for (int r = 0; r < 32; ++r)
      xz[(size_t)(row0 + r) * G4 + q * 256 + tid] = acc[q][r] + bb;
  }
}

// ---------------------------------------------------------------------------
// Kernel 2: LSTM recurrence, 8 slice-WGs per batch (128 WGs x 512 threads).
// R14 protocol (measured floor): far-only (sc0 sc1) checksummed mailbox
// chunks {h0,h1,h0^h1^stamp,0}, stamp=(t+1)|(kid<<20), slot parity t&1,
// pacing barrier after stores, single far probe per poll iteration,
// 32-lane pointwise (R14: -48us).
// NEW vs R14: poll fan-out reduced 4x — only threads 0..127 poll, each a
// DISTINCT chunk (was: 512 threads, 4x redundant). Pollers deposit h into
// LDS hbuf[256]; one barrier; all threads read hv from LDS. Rationale:
// measured ledger (R7/R9/R12/R13) shows probe TRAFFIC is the latency tax —
// every extra probe class cost 20-60us; this cuts machine-wide probe rate
// 4x for ~100cyc of LDS/barrier overhead. Protocol semantics unchanged.
// ---------------------------------------------------------------------------
__device__ __forceinline__ void lstm_body(
    char* pool, int bid,
    const float* __restrict__ xz, const float* __restrict__ Wr,
    const float* __restrict__ h0, int h0_stride,
    const float* __restrict__ cinit,
    float* __restrict__ Hout, float* __restrict__ c_fin,
    i32x4* __restrict__ fmb, int kid, int T)
{
  float (*part)[4][128] = (float (*)[4][128])pool;         // 4 KB (x2 parity)
  float* hbuf           = (float*)(pool + 4096);           // 1 KB h broadcast
  float (*xbuf)[128]    = (float (*)[128])(pool + 5120);   // 56 KB

  const int b    = bid & (BB - 1);
  const int s    = bid >> 4;
  const int tid  = threadIdx.x;
  const int lane = tid & 63;
  const int quarter = tid >> 7;        // 0..3 : h-dim range quarter*64..+64
  const int col  = tid & 127;          // gate col within slice
  const int gate = col >> 5, u = col & 31;

  // weight column slice in registers
  float w_r[64];
  {
    const float* wp = Wr + (size_t)(quarter * 64) * G4 + gate * 256 + s * 32 + u;
#pragma unroll
    for (int j = 0; j < 64; ++j) w_r[j] = wp[(size_t)j * G4];
  }

  const int i0 = quarter * 64 + lane;
  float hv = 0.0f;
  if (h0) hv = h0[(size_t)b * h0_stride + i0];

  // pointwise: 32 lanes, one unit each (R14)
  const int pu = (tid < 16) ? (2 * tid) : (2 * (tid - 16) + 1);
  float cs = 0.0f;
  if (tid < 32 && cinit) cs = cinit[b * HID + s * 32 + pu];

  int tp = XROWS;
  for (int t = 0; t < T; ++t, ++tp) {
    // ---- periodic xz burst into LDS ----
    if (tp >= XROWS) {
      __syncthreads();               // all readers of old xbuf are done
      tp = 0;
      for (int tt = quarter; tt < XROWS; tt += 4) {
        int ts = t + tt;
        if (ts < T)
          xbuf[tt][col] = xz[((size_t)b * T + ts) * G4 + gate * 256 + s * 32 + u];
      }
    }

    // ---- partial dot over this quarter's 64 h values (4 chains) ----
    float a0 = 0.0f, a1 = 0.0f, a2 = 0.0f, a3 = 0.0f;
#pragma unroll
    for (int j = 0; j < 64; j += 4) {
      a0 = fmaf(__int_as_float(__builtin_amdgcn_readlane(__float_as_int(hv), j + 0)), w_r[j + 0], a0);
      a1 = fmaf(__int_as_float(__builtin_amdgcn_readlane(__float_as_int(hv), j + 1)), w_r[j + 1], a1);
      a2 = fmaf(__int_as_float(__builtin_amdgcn_readlane(__float_as_int(hv), j + 2)), w_r[j + 2], a2);
      a3 = fmaf(__int_as_float(__builtin_amdgcn_readlane(__float_as_int(hv), j + 3)), w_r[j + 3], a3);
    }
    part[t & 1][quarter][col] = (a0 + a1) + (a2 + a3);
    __syncthreads();                 // part ready

    const int stamp = (t + 1) | (kid << 20);
    const size_t slot = (size_t)(b * 2 + (t & 1)) * 128;

    // ---- pointwise (lanes 0..31, one unit each); publish from 0..15 ----
    if (tid < 32) {
      const float (*pp)[128] = part[t & 1];
      float zi = pp[0][pu]      + pp[1][pu]      + pp[2][pu]      + pp[3][pu]
               + xbuf[tp][pu];
      float zf = pp[0][32 + pu] + pp[1][32 + pu] + pp[2][32 + pu] + pp[3][32 + pu]
               + xbuf[tp][32 + pu];
      float zg = pp[0][64 + pu] + pp[1][64 + pu] + pp[2][64 + pu] + pp[3][64 + pu]
               + xbuf[tp][64 + pu];
      float zo = pp[0][96 + pu] + pp[1][96 + pu] + pp[2][96 + pu] + pp[3][96 + pu]
               + xbuf[tp][96 + pu];

      cs = fmaf(sigf(zf), cs, sigf(zi) * tanhfast(zg));
      float h = sigf(zo) * tanhfast(cs);

      float hodd = __shfl_down(h, 16, 64);   // lanes 0..15 <- lanes 16..31

      if (tid < 16) {
        const int ua = 2 * tid;
        *(float2*)&Hout[((size_t)b * T + t) * HID + s * 32 + ua] =
            make_float2(h, hodd);

        i32x4 ch;
        ch.x = __float_as_int(h);
        ch.y = __float_as_int(hodd);
        ch.z = ch.x ^ ch.y ^ stamp;
        ch.w = 0;
        const i32x4* fd = fmb + slot + s * 16 + tid;
        asm volatile("global_store_dwordx4 %0, %1, off sc0 sc1"
                     :: "v"(fd), "v"(ch) : "memory");
      }
    }
    __syncthreads();   // pacing: stores drained (vmcnt in barrier) before polls

    // ---- poll h(t): threads 0..127 poll ONE distinct chunk each, deposit
    //      into LDS; barrier; everyone reads hv. 4x fewer probes than R14.
    if (t + 1 < T) {
      if (tid < 128) {
        const i32x4* fp = fmb + slot + tid;
        i32x4 v;
        for (;;) {
          asm volatile("global_load_dwordx4 %0, %1, off sc0 sc1\n\t"
                       "s_waitcnt vmcnt(0)"
                       : "=&v"(v) : "v"(fp) : "memory");
          if (v.z == (v.x ^ v.y ^ stamp)) break;
        }
        hbuf[2 * tid]     = __int_as_float(v.x);
        hbuf[2 * tid + 1] = __int_as_float(v.y);
      }
      __syncthreads();
      hv = hbuf[i0];
    }
  }
  if (c_fin && tid < 32) c_fin[b * HID + s * 32 + pu] = cs;
}

__global__ __launch_bounds__(512, 1) void lstm_kernel(
    const float* __restrict__ xz, const float* __restrict__ Wr,
    const float* __restrict__ h0, int h0_stride,
    const float* __restrict__ cinit,
    float* __restrict__ Hout, float* __restrict__ c_fin,
    i32x4* __restrict__ fmb, int kid, int T)
{
  extern __shared__ char pool[];
  lstm_body(pool, blockIdx.x, xz, Wr, h0, h0_stride, cinit,
            Hout, c_fin, fmb, kid, T);
}

// ---------------------------------------------------------------------------
// Kernel 3 (merged): blocks [0,4000): prepack WoutT[n][k] = bf16(Wout[k][n]);
// blocks [4000,6048): attention + bf16 feat pack.  (R10-proven)
// ---------------------------------------------------------------------------
__global__ __launch_bounds__(256) void mid_kernel(
    const float* __restrict__ W, ushort_t* __restrict__ WT,
    const float* __restrict__ Henc, const float* __restrict__ S,
    __hip_bfloat16* __restrict__ featB)
{
  const int tid = threadIdx.x;

  if (blockIdx.x < 4000) {
    // ---------------- prepack ----------------
    __shared__ float tile[64][65];
    const int nt = blockIdx.x % 500;
    const int kt = blockIdx.x / 500;
    const int n0 = nt * 64, k0 = kt * 64;
    const int r = tid >> 6, c = tid & 63;

#pragma unroll
    for (int q = 0; q < 16; ++q) {
      int kk = q * 4 + r;
      tile[kk][c] = W[(size_t)(k0 + kk) * VOCAB + n0 + c];
    }
    __syncthreads();

    const int nl = tid >> 2;             // 0..63 output row
    const int seg = (tid & 3) * 16;      // 16 k per thread
    uint_t o[8];
#pragma unroll
    for (int j = 0; j < 8; ++j) {
      uint_t lo = bf16_rne(tile[seg + 2 * j][nl]);
      uint_t hi = bf16_rne(tile[seg + 2 * j + 1][nl]);
      o[j] = lo | (hi << 16);
    }
    ushort_t* dst = WT + (size_t)(n0 + nl) * 512 + k0 + seg;
    ((uint4*)dst)[0] = make_uint4(o[0], o[1], o[2], o[3]);
    ((uint4*)dst)[1] = make_uint4(o[4], o[5], o[6], o[7]);
  } else {
    // ---------------- attention ----------------
    __shared__ float srow[HID];
    __shared__ float p[LS];
    __shared__ float sm[LS];

    const int m = blockIdx.x - 4000;   // b*LT + t
    const int b = m >> 7, t = m & (LT - 1);

    const float* s_ = (t == 0) ? (Henc + ((size_t)b * LS + (LS - 1)) * HID)
                               : (S + (size_t)(m - 1) * HID);
    srow[tid] = s_[tid];
    __syncthreads();

    const float4* h4 = (const float4*)(Henc + ((size_t)b * LS + tid) * HID);
    const float4* s4 = (const float4*)srow;
    float sc = 0.0f;
#pragma unroll 8
    for (int k = 0; k < HID / 4; ++k) {
      float4 a = h4[k], q = s4[k];
      sc += a.x * q.x + a.y * q.y + a.z * q.z + a.w * q.w;
    }
    sm[tid] = sc;
    __syncthreads();
    for (int st = 128; st > 0; st >>= 1) {
      if (tid < st) sm[tid] = fmaxf(sm[tid], sm[tid + st]);
      __syncthreads();
    }
    float mx = sm[0];
    __syncthreads();
    float e = __expf(sc - mx);
    p[tid] = e;
    sm[tid] = e;
    __syncthreads();
    for (int st = 128; st > 0; st >>= 1) {
      if (tid < st) sm[tid] += sm[tid + st];
      __syncthreads();
    }
    float inv = 1.0f / sm[0];

    float a_d = 0.0f;
#pragma unroll 4
    for (int s2 = 0; s2 < LS; ++s2)
      a_d = fmaf(p[s2], Henc[((size_t)b * LS + s2) * HID + tid], a_d);
    a_d *= inv;

    featB[(size_t)m * (2 * HID) + tid]       = __float2bfloat16(S[(size_t)m * HID + tid]);
    featB[(size_t)m * (2 * HID) + HID + tid] = __float2bfloat16(a_d);
  }
}

// ---------------------------------------------------------------------------
// Kernel 4: logits GEMM, 128x128 tile, BK=64, double-buffered LDS,
// global_load_lds width=16 staging (R12-verified). Linear LDS dest +
// source-side XOR swizzle (rule-21 both-sides involution).
// Epilogue: E = exp(logit+bias) stored unnormalized + rowsum atomics.
// ---------------------------------------------------------------------------
__global__ __launch_bounds__(256) void proj_exp_kernel(
    const ushort_t* __restrict__ A, const ushort_t* __restrict__ BT,
    const float* __restrict__ bout, float* __restrict__ rowsum,
    float* __restrict__ out)
{
  __shared__ ushort_t Ab[2][128 * 64];   // 16 KB each
  __shared__ ushort_t Bb[2][128 * 64];

  const int bid = blockIdx.x;
  const int k2 = (bid & 7) * 500 + (bid >> 3);   // XCD-chunked
  const int mt = k2 & 15, nt = k2 >> 4;          // 16 x 250
  const int m0 = mt * 128, n0 = nt * 128;
  const int tid = threadIdx.x;
  const int wave = tid >> 6, lane = tid & 63;
  const int wm = wave >> 1, wn = wave & 1;
  const int r = lane & 15, kg = lane >> 4;

  const ushort_t* Ag = A + (size_t)m0 * 512;
  const ushort_t* Bg = BT + (size_t)n0 * 512;

  f32x4 acc[4][4];
#pragma unroll
  for (int i = 0; i < 4; ++i)
#pragma unroll
    for (int j = 0; j < 4; ++j) acc[i][j] = (f32x4){0.f, 0.f, 0.f, 0.f};

  // async global->LDS staging: linear LDS dest, swizzled global source
#define STAGE(kc, buf)                                                        \
  {                                                                           \
    _Pragma("unroll")                                                         \
    for (int q = 0; q < 4; ++q) {                                             \
      int L = q * 256 + tid;                                                  \
      int row_ = L >> 3, seg_ = L & 7;                                        \
      int sseg_ = seg_ ^ (row_ & 7);                                          \
      int wbase = (q * 256 + (tid & ~63)) * 8;  /* wave-uniform ushort idx */ \
      __builtin_amdgcn_global_load_lds(                                       \
          (const __attribute__((address_space(1))) unsigned int*)             \
              (Ag + (size_t)row_ * 512 + (kc) * 64 + sseg_ * 8),              \
          (__attribute__((address_space(3))) unsigned int*)&Ab[buf][wbase],   \
          16, 0, 0);                                                          \
      __builtin_amdgcn_global_load_lds(                                       \
          (const __attribute__((address_space(1))) unsigned int*)             \
              (Bg + (size_t)row_ * 512 + (kc) * 64 + sseg_ * 8),              \
          (__attribute__((address_space(3))) unsigned int*)&Bb[buf][wbase],   \
          16, 0, 0);                                                          \
    }                                                                         \
  }

  STAGE(0, 0);
  __syncthreads();

  for (int kc = 0; kc < 8; ++kc) {
    const int cur = kc & 1;
    if (kc < 7) STAGE(kc + 1, cur ^ 1);
#pragma unroll
    for (int ks = 0; ks < 2; ++ks) {
      bf16x8 a[4], b[4];
      const int seg = ks * 4 + kg;
#pragma unroll
      for (int i = 0; i < 4; ++i) {
        int row = wm * 64 + i * 16 + r;
        a[i] = *(const bf16x8*)&Ab[cur][row * 64 + ((seg ^ (row & 7)) << 3)];
      }
#pragma unroll
      for (int j = 0; j < 4; ++j) {
        int row = wn * 64 + j * 16 + r;
        b[j] = *(const bf16x8*)&Bb[cur][row * 64 + ((seg ^ (row & 7)) << 3)];
      }
#pragma unroll
      for (int i = 0; i < 4; ++i)
#pragma unroll
        for (int j = 0; j < 4; ++j)
          acc[i][j] = __builtin_amdgcn_mfma_f32_16x16x32_bf16(a[i], b[j], acc[i][j], 0, 0, 0);
    }
    __syncthreads();
  }
#undef STAGE

  float bv[4];
#pragma unroll
  for (int j = 0; j < 4; ++j) bv[j] = bout[n0 + wn * 64 + j * 16 + r];

#pragma unroll
  for (int i = 0; i < 4; ++i)
#pragma unroll
    for (int q = 0; q < 4; ++q) {
      const int row = m0 + wm * 64 + i * 16 + kg * 4 + q;
      float v = 0.0f;
#pragma unroll
      for (int j = 0; j < 4; ++j) {
        float e = __expf(acc[i][j][q] + bv[j]);
        out[(size_t)row * VOCAB + n0 + wn * 64 + j * 16 + r] = e;
        v += e;
      }
#pragma unroll
      for (int msk = 1; msk < 16; msk <<= 1) v += __shfl_xor(v, msk, 64);
      if (r == 0) atomicAdd(&rowsum[row], v);
    }
}

// Kernel 5: out *= 1/rowsum[row]. 4 blocks per row.
__global__ __launch_bounds__(256) void scale_kernel(
    float* __restrict__ out, const float* __restrict__ rowsum)
{
  const int row = blockIdx.x >> 2;       // 0..2047
  const int seg = blockIdx.x & 3;        // 4 segments of 2000 float4
  const float s = 1.0f / rowsum[row];
  float4* o4 = (float4*)(out + (size_t)row * VOCAB) + seg * 2000;
  for (int i = threadIdx.x; i < 2000; i += 256) {
    float4 v = o4[i];
    v.x *= s; v.y *= s; v.z *= s; v.w *= s;
    o4[i] = v;
  }
}

// ---------------------------------------------------------------------------
// Host launcher
// ---------------------------------------------------------------------------
extern "C" void kernel_launch(void* const* d_in, const int* in_sizes, int n_in,
                              void* d_out, int out_size, void* d_ws, size_t ws_size,
                              hipStream_t stream) {
  (void)in_sizes; (void)n_in; (void)out_size; (void)ws_size;

  const int*   x       = (const int*)d_in[0];
  const int*   y       = (const int*)d_in[1];
  const float* enc_emb = (const float*)d_in[2];
  const float* enc_Wk  = (const float*)d_in[3];
  const float* enc_Wr  = (const float*)d_in[4];
  const float* enc_b   = (const float*)d_in[5];
  const float* dec_emb = (const float*)d_in[6];
  const float* dec_Wk  = (const float*)d_in[7];
  const float* dec_Wr  = (const float*)d_in[8];
  const float* dec_b   = (const float*)d_in[9];
  const float* Wout    = (const float*)d_in[10];
  const float* bout    = (const float*)d_in[11];
  float* out = (float*)d_out;
  char*  ws  = (char*)d_ws;

  // workspace layout (bytes); rowsum+fmb contiguous -> ONE memset
  size_t off = 0;
  float* xz_enc = (float*)(ws + off); off += (size_t)BB * LS * G4 * 4;      // 16 MB
  float* xz_dec = (float*)(ws + off); off += (size_t)BB * LT * G4 * 4;      //  8 MB
  float* Henc   = (float*)(ws + off); off += (size_t)BB * LS * HID * 4;     //  4 MB
  float* S      = (float*)(ws + off); off += (size_t)BB * LT * HID * 4;     //  2 MB
  __hip_bfloat16* featB = (__hip_bfloat16*)(ws + off);
  off += (size_t)BB * LT * 2 * HID * 2;                                     //  2 MB
  ushort_t* WoutT = (ushort_t*)(ws + off); off += (size_t)VOCAB * 512 * 2;  // 32 MB
  float* c_fin  = (float*)(ws + off); off += (size_t)BB * HID * 4;
  size_t zero_base = off;
  float* rowsum = (float*)(ws + off); off += (size_t)BB * LT * 4;           //  8 KB
  i32x4* fmb    = (i32x4*)(ws + off); off += (size_t)BB * 2 * 128 * 16;     // 64 KB
  size_t zero_len = off - zero_base;

  hipMemsetAsync(ws + zero_base, 0, zero_len, stream);

  // input projections (enc + dec in one launch)
  embed_proj_kernel<<<192, 256, 0, stream>>>(
      x, y, enc_emb, enc_Wk, enc_b, dec_emb, dec_Wk, dec_b, xz_enc, xz_dec);

  // encoder LSTM (h0=c0=0): 128 WGs x 512 threads
  lstm_kernel<<<NSL * BB, 512, LSTM_POOL, stream>>>(
      xz_enc, enc_Wr, nullptr, 0, nullptr, Henc, c_fin, fmb, 0, LS);

  // decoder LSTM (h0 = enc final h rows inside Henc, c0 = c_fin)
  lstm_kernel<<<NSL * BB, 512, LSTM_POOL, stream>>>(
      xz_dec, dec_Wr, Henc + (size_t)(LS - 1) * HID, LS * HID, c_fin,
      S, nullptr, fmb, 1, LT);

  // prepack + attention in one launch
  mid_kernel<<<4000 + BB * LT, 256, 0, stream>>>(
      Wout, WoutT, Henc, S, (__hip_bfloat16*)featB);

  // GEMM + exp (unnormalized) + rowsum; then scale
  proj_exp_kernel<<<16 * 250, 256, 0, stream>>>(
      (const ushort_t*)featB, WoutT, bout, rowsum, out);
  scale_kernel<<<4 * BB * LT, 256, 0, stream>>>(out, rowsum);
}

// Round 16
// 1054.090 us; speedup vs baseline: 1.0080x; 1.0080x over previous
//
#include <hip/hip_runtime.h>
#include <hip/hip_bf16.h>
#include <math.h>

// Problem constants
#define BB    16
#define LS    256
#define LT    128
#define EMB   128
#define HID   256
#define G4    1024      // 4*HID
#define VOCAB 32000

// LSTM slicing: 8 slice-WGs per batch, 512 threads each. (R10/R14-proven)
#define NSL   8
#define XROWS 112      // LDS-staged xz steps per burst (56 KB)
#define LSTM_POOL (4096 + XROWS * 128 * 4)   // 61440 B

typedef __attribute__((ext_vector_type(8))) short bf16x8;
typedef __attribute__((ext_vector_type(4))) float f32x4;
typedef __attribute__((ext_vector_type(4))) int   i32x4;
typedef unsigned short ushort_t;
typedef unsigned int uint_t;

__device__ inline float sigf(float x)      { return 1.0f / (1.0f + __expf(-x)); }
__device__ inline float tanhfast(float x)  { return 1.0f - 2.0f / (1.0f + __expf(2.0f * x)); }
__device__ inline ushort_t bf16_rne(float f) {
  __hip_bfloat16 h = __float2bfloat16(f);
  return *(ushort_t*)&h;
}

// ---------------------------------------------------------------------------
// Kernel 1: xz = emb[idx] @ Wk + b for BOTH enc and dec (one launch).
// ---------------------------------------------------------------------------
__global__ __launch_bounds__(256) void embed_proj_kernel(
    const int* __restrict__ x, const int* __restrict__ y,
    const float* __restrict__ eemb, const float* __restrict__ eWk,
    const float* __restrict__ eb,
    const float* __restrict__ demb, const float* __restrict__ dWk,
    const float* __restrict__ db,
    float* __restrict__ xze, float* __restrict__ xzd)
{
  const bool enc = blockIdx.x < 128;
  const int* idx = enc ? x : y;
  const float* emb = enc ? eemb : demb;
  const float* Wk  = enc ? eWk  : dWk;
  const float* bias= enc ? eb   : db;
  float* xz        = enc ? xze  : xzd;
  const int row0 = (enc ? blockIdx.x : blockIdx.x - 128) * 32;

  __shared__ float e[32][EMB];    // 16 KB
  const int tid = threadIdx.x;

  for (int i = tid; i < 32 * EMB; i += 256) {
    int r = i >> 7, k = i & 127;
    int token = idx[row0 + r];
    e[r][k] = emb[(size_t)token * EMB + k];
  }
  __syncthreads();

  float acc[4][32];
#pragma unroll
  for (int q = 0; q < 4; ++q)
#pragma unroll
    for (int r = 0; r < 32; ++r) acc[q][r] = 0.0f;

  for (int k = 0; k < EMB; ++k) {
    float w0 = Wk[(size_t)k * G4 + 0 * 256 + tid];
    float w1 = Wk[(size_t)k * G4 + 1 * 256 + tid];
    float w2 = Wk[(size_t)k * G4 + 2 * 256 + tid];
    float w3 = Wk[(size_t)k * G4 + 3 * 256 + tid];
#pragma unroll
    for (int r = 0; r < 32; ++r) {
      float ev = e[r][k];
      acc[0][r] = fmaf(ev, w0, acc[0][r]);
      acc[1][r] = fmaf(ev, w1, acc[1][r]);
      acc[2][r] = fmaf(ev, w2, acc[2][r]);
      acc[3][r] = fmaf(ev, w3, acc[3][r]);
    }
  }
#pragma unroll
  for (int q = 0; q < 4; ++q) {
    float bb = bias[q * 256 + tid];
#pragma unroll
    for (int r = 0; r < 32; ++r)
      xz[(size_t)(row0 + r) * G4 + q * 256 + tid] = acc[q][r] + bb;
  }
}

// ---------------------------------------------------------------------------
// Kernel 2: LSTM recurrence, 8 slice-WGs per batch (128 WGs x 512 threads).
// R14-EXACT (measured floor): far-only (sc0 sc1) checksummed mailbox chunks
// {h0,h1,h0^h1^stamp,0}, stamp=(t+1)|(kid<<20), slot parity t&1, pacing
// barrier after stores, SINGLE far probe per poll iteration (all 512
// threads), 32-lane pointwise. Sync ledger — all rejected by measurement:
// near-L2 probes (R7/R9), sticky-near (R8 hang), no-barrier (R7), 2-deep
// pipelined poll (R12), batch-pairing (R13), reduced poll fan-out + LDS
// broadcast (R15: +17us). This structure is the protocol floor.
// ---------------------------------------------------------------------------
__device__ __forceinline__ void lstm_body(
    char* pool, int bid,
    const float* __restrict__ xz, const float* __restrict__ Wr,
    const float* __restrict__ h0, int h0_stride,
    const float* __restrict__ cinit,
    float* __restrict__ Hout, float* __restrict__ c_fin,
    i32x4* __restrict__ fmb, int kid, int T)
{
  float (*part)[4][128] = (float (*)[4][128])pool;         // 4 KB (x2 parity)
  float (*xbuf)[128]    = (float (*)[128])(pool + 4096);   // 56 KB

  const int b    = bid & (BB - 1);
  const int s    = bid >> 4;
  const int tid  = threadIdx.x;
  const int lane = tid & 63;
  const int quarter = tid >> 7;        // 0..3 : h-dim range quarter*64..+64
  const int col  = tid & 127;          // gate col within slice
  const int gate = col >> 5, u = col & 31;

  // weight column slice in registers
  float w_r[64];
  {
    const float* wp = Wr + (size_t)(quarter * 64) * G4 + gate * 256 + s * 32 + u;
#pragma unroll
    for (int j = 0; j < 64; ++j) w_r[j] = wp[(size_t)j * G4];
  }

  const int i0 = quarter * 64 + lane;
  float hv = 0.0f;
  if (h0) hv = h0[(size_t)b * h0_stride + i0];

  // pointwise: 32 lanes, one unit each; lanes 0..15 even units, 16..31 odd.
  const int pu = (tid < 16) ? (2 * tid) : (2 * (tid - 16) + 1);
  float cs = 0.0f;
  if (tid < 32 && cinit) cs = cinit[b * HID + s * 32 + pu];

  const int c0i = i0 >> 1;   // mailbox chunk holding h[i0]
  const int sel = i0 & 1;

  int tp = XROWS;
  for (int t = 0; t < T; ++t, ++tp) {
    // ---- periodic xz burst into LDS ----
    if (tp >= XROWS) {
      __syncthreads();               // all readers of old xbuf are done
      tp = 0;
      for (int tt = quarter; tt < XROWS; tt += 4) {
        int ts = t + tt;
        if (ts < T)
          xbuf[tt][col] = xz[((size_t)b * T + ts) * G4 + gate * 256 + s * 32 + u];
      }
    }

    // ---- partial dot over this quarter's 64 h values (4 chains) ----
    float a0 = 0.0f, a1 = 0.0f, a2 = 0.0f, a3 = 0.0f;
#pragma unroll
    for (int j = 0; j < 64; j += 4) {
      a0 = fmaf(__int_as_float(__builtin_amdgcn_readlane(__float_as_int(hv), j + 0)), w_r[j + 0], a0);
      a1 = fmaf(__int_as_float(__builtin_amdgcn_readlane(__float_as_int(hv), j + 1)), w_r[j + 1], a1);
      a2 = fmaf(__int_as_float(__builtin_amdgcn_readlane(__float_as_int(hv), j + 2)), w_r[j + 2], a2);
      a3 = fmaf(__int_as_float(__builtin_amdgcn_readlane(__float_as_int(hv), j + 3)), w_r[j + 3], a3);
    }
    part[t & 1][quarter][col] = (a0 + a1) + (a2 + a3);
    __syncthreads();                 // part ready

    const int stamp = (t + 1) | (kid << 20);
    const size_t slot = (size_t)(b * 2 + (t & 1)) * 128;

    // ---- pointwise (lanes 0..31, one unit each); publish from 0..15 ----
    if (tid < 32) {
      const float (*pp)[128] = part[t & 1];
      float zi = pp[0][pu]      + pp[1][pu]      + pp[2][pu]      + pp[3][pu]
               + xbuf[tp][pu];
      float zf = pp[0][32 + pu] + pp[1][32 + pu] + pp[2][32 + pu] + pp[3][32 + pu]
               + xbuf[tp][32 + pu];
      float zg = pp[0][64 + pu] + pp[1][64 + pu] + pp[2][64 + pu] + pp[3][64 + pu]
               + xbuf[tp][64 + pu];
      float zo = pp[0][96 + pu] + pp[1][96 + pu] + pp[2][96 + pu] + pp[3][96 + pu]
               + xbuf[tp][96 + pu];

      cs = fmaf(sigf(zf), cs, sigf(zi) * tanhfast(zg));
      float h = sigf(zo) * tanhfast(cs);

      float hodd = __shfl_down(h, 16, 64);   // lanes 0..15 <- lanes 16..31

      if (tid < 16) {
        const int ua = 2 * tid;
        *(float2*)&Hout[((size_t)b * T + t) * HID + s * 32 + ua] =
            make_float2(h, hodd);

        i32x4 ch;
        ch.x = __float_as_int(h);
        ch.y = __float_as_int(hodd);
        ch.z = ch.x ^ ch.y ^ stamp;
        ch.w = 0;
        const i32x4* fd = fmb + slot + s * 16 + tid;
        asm volatile("global_store_dwordx4 %0, %1, off sc0 sc1"
                     :: "v"(fd), "v"(ch) : "memory");
      }
    }
    __syncthreads();   // pacing: stores drained (vmcnt in barrier) before polls

    // ---- poll h(t): far-only single probe (R14-proven floor) ----
    if (t + 1 < T) {
      const i32x4* fp = fmb + slot + c0i;
      i32x4 v;
      for (;;) {
        asm volatile("global_load_dwordx4 %0, %1, off sc0 sc1\n\t"
                     "s_waitcnt vmcnt(0)"
                     : "=&v"(v) : "v"(fp) : "memory");
        if (v.z == (v.x ^ v.y ^ stamp)) break;
      }
      hv = __int_as_float(sel ? v.y : v.x);
    }
  }
  if (c_fin && tid < 32) c_fin[b * HID + s * 32 + pu] = cs;
}

__global__ __launch_bounds__(512, 1) void lstm_kernel(
    const float* __restrict__ xz, const float* __restrict__ Wr,
    const float* __restrict__ h0, int h0_stride,
    const float* __restrict__ cinit,
    float* __restrict__ Hout, float* __restrict__ c_fin,
    i32x4* __restrict__ fmb, int kid, int T)
{
  extern __shared__ char pool[];
  lstm_body(pool, blockIdx.x, xz, Wr, h0, h0_stride, cinit,
            Hout, c_fin, fmb, kid, T);
}

// ---------------------------------------------------------------------------
// Kernel 3 (merged): blocks [0,2048): attention + bf16 feat pack (FIRST —
// longest per-block latency, so it overlaps prepack instead of serializing
// after it); blocks [2048,6048): prepack WoutT[n][k] = bf16(Wout[k][n]).
// Attention PV loop: 4 independent FMA chains (was a 256-long serial chain).
// ---------------------------------------------------------------------------
__global__ __launch_bounds__(256) void mid_kernel(
    const float* __restrict__ W, ushort_t* __restrict__ WT,
    const float* __restrict__ Henc, const float* __restrict__ S,
    __hip_bfloat16* __restrict__ featB)
{
  const int tid = threadIdx.x;

  if (blockIdx.x >= 2048) {
    // ---------------- prepack ----------------
    __shared__ float tile[64][65];
    const int tix = blockIdx.x - 2048;
    const int nt = tix % 500;
    const int kt = tix / 500;
    const int n0 = nt * 64, k0 = kt * 64;
    const int r = tid >> 6, c = tid & 63;

#pragma unroll
    for (int q = 0; q < 16; ++q) {
      int kk = q * 4 + r;
      tile[kk][c] = W[(size_t)(k0 + kk) * VOCAB + n0 + c];
    }
    __syncthreads();

    const int nl = tid >> 2;             // 0..63 output row
    const int seg = (tid & 3) * 16;      // 16 k per thread
    uint_t o[8];
#pragma unroll
    for (int j = 0; j < 8; ++j) {
      uint_t lo = bf16_rne(tile[seg + 2 * j][nl]);
      uint_t hi = bf16_rne(tile[seg + 2 * j + 1][nl]);
      o[j] = lo | (hi << 16);
    }
    ushort_t* dst = WT + (size_t)(n0 + nl) * 512 + k0 + seg;
    ((uint4*)dst)[0] = make_uint4(o[0], o[1], o[2], o[3]);
    ((uint4*)dst)[1] = make_uint4(o[4], o[5], o[6], o[7]);
  } else {
    // ---------------- attention ----------------
    __shared__ float srow[HID];
    __shared__ float p[LS];
    __shared__ float sm[LS];

    const int m = blockIdx.x;          // b*LT + t
    const int b = m >> 7, t = m & (LT - 1);

    const float* s_ = (t == 0) ? (Henc + ((size_t)b * LS + (LS - 1)) * HID)
                               : (S + (size_t)(m - 1) * HID);
    srow[tid] = s_[tid];
    __syncthreads();

    const float4* h4 = (const float4*)(Henc + ((size_t)b * LS + tid) * HID);
    const float4* s4 = (const float4*)srow;
    float sc = 0.0f;
#pragma unroll 8
    for (int k = 0; k < HID / 4; ++k) {
      float4 a = h4[k], q = s4[k];
      sc += a.x * q.x + a.y * q.y + a.z * q.z + a.w * q.w;
    }
    sm[tid] = sc;
    __syncthreads();
    for (int st = 128; st > 0; st >>= 1) {
      if (tid < st) sm[tid] = fmaxf(sm[tid], sm[tid + st]);
      __syncthreads();
    }
    float mx = sm[0];
    __syncthreads();
    float e = __expf(sc - mx);
    p[tid] = e;
    sm[tid] = e;
    __syncthreads();
    for (int st = 128; st > 0; st >>= 1) {
      if (tid < st) sm[tid] += sm[tid + st];
      __syncthreads();
    }
    float inv = 1.0f / sm[0];

    // PV: 4 independent chains (ILP on the load-use path)
    const float* hb = Henc + (size_t)b * LS * HID + tid;
    float a0 = 0.0f, a1 = 0.0f, a2 = 0.0f, a3 = 0.0f;
#pragma unroll 2
    for (int s2 = 0; s2 < LS; s2 += 4) {
      a0 = fmaf(p[s2 + 0], hb[(size_t)(s2 + 0) * HID], a0);
      a1 = fmaf(p[s2 + 1], hb[(size_t)(s2 + 1) * HID], a1);
      a2 = fmaf(p[s2 + 2], hb[(size_t)(s2 + 2) * HID], a2);
      a3 = fmaf(p[s2 + 3], hb[(size_t)(s2 + 3) * HID], a3);
    }
    float a_d = ((a0 + a1) + (a2 + a3)) * inv;

    featB[(size_t)m * (2 * HID) + tid]       = __float2bfloat16(S[(size_t)m * HID + tid]);
    featB[(size_t)m * (2 * HID) + HID + tid] = __float2bfloat16(a_d);
  }
}

// ---------------------------------------------------------------------------
// Kernel 4: logits GEMM, 128x128 tile, BK=64, double-buffered LDS,
// global_load_lds width=16 staging (R12-verified). Linear LDS dest +
// source-side XOR swizzle (rule-21 both-sides involution).
// Epilogue: E = exp(logit+bias) stored unnormalized + rowsum atomics.
// ---------------------------------------------------------------------------
__global__ __launch_bounds__(256) void proj_exp_kernel(
    const ushort_t* __restrict__ A, const ushort_t* __restrict__ BT,
    const float* __restrict__ bout, float* __restrict__ rowsum,
    float* __restrict__ out)
{
  __shared__ ushort_t Ab[2][128 * 64];   // 16 KB each
  __shared__ ushort_t Bb[2][128 * 64];

  const int bid = blockIdx.x;
  const int k2 = (bid & 7) * 500 + (bid >> 3);   // XCD-chunked
  const int mt = k2 & 15, nt = k2 >> 4;          // 16 x 250
  const int m0 = mt * 128, n0 = nt * 128;
  const int tid = threadIdx.x;
  const int wave = tid >> 6, lane = tid & 63;
  const int wm = wave >> 1, wn = wave & 1;
  const int r = lane & 15, kg = lane >> 4;

  const ushort_t* Ag = A + (size_t)m0 * 512;
  const ushort_t* Bg = BT + (size_t)n0 * 512;

  f32x4 acc[4][4];
#pragma unroll
  for (int i = 0; i < 4; ++i)
#pragma unroll
    for (int j = 0; j < 4; ++j) acc[i][j] = (f32x4){0.f, 0.f, 0.f, 0.f};

  // async global->LDS staging: linear LDS dest, swizzled global source
#define STAGE(kc, buf)                                                        \
  {                                                                           \
    _Pragma("unroll")                                                         \
    for (int q = 0; q < 4; ++q) {                                             \
      int L = q * 256 + tid;                                                  \
      int row_ = L >> 3, seg_ = L & 7;                                        \
      int sseg_ = seg_ ^ (row_ & 7);                                          \
      int wbase = (q * 256 + (tid & ~63)) * 8;  /* wave-uniform ushort idx */ \
      __builtin_amdgcn_global_load_lds(                                       \
          (const __attribute__((address_space(1))) unsigned int*)             \
              (Ag + (size_t)row_ * 512 + (kc) * 64 + sseg_ * 8),              \
          (__attribute__((address_space(3))) unsigned int*)&Ab[buf][wbase],   \
          16, 0, 0);                                                          \
      __builtin_amdgcn_global_load_lds(                                       \
          (const __attribute__((address_space(1))) unsigned int*)             \
              (Bg + (size_t)row_ * 512 + (kc) * 64 + sseg_ * 8),              \
          (__attribute__((address_space(3))) unsigned int*)&Bb[buf][wbase],   \
          16, 0, 0);                                                          \
    }                                                                         \
  }

  STAGE(0, 0);
  __syncthreads();

  for (int kc = 0; kc < 8; ++kc) {
    const int cur = kc & 1;
    if (kc < 7) STAGE(kc + 1, cur ^ 1);
#pragma unroll
    for (int ks = 0; ks < 2; ++ks) {
      bf16x8 a[4], b[4];
      const int seg = ks * 4 + kg;
#pragma unroll
      for (int i = 0; i < 4; ++i) {
        int row = wm * 64 + i * 16 + r;
        a[i] = *(const bf16x8*)&Ab[cur][row * 64 + ((seg ^ (row & 7)) << 3)];
      }
#pragma unroll
      for (int j = 0; j < 4; ++j) {
        int row = wn * 64 + j * 16 + r;
        b[j] = *(const bf16x8*)&Bb[cur][row * 64 + ((seg ^ (row & 7)) << 3)];
      }
#pragma unroll
      for (int i = 0; i < 4; ++i)
#pragma unroll
        for (int j = 0; j < 4; ++j)
          acc[i][j] = __builtin_amdgcn_mfma_f32_16x16x32_bf16(a[i], b[j], acc[i][j], 0, 0, 0);
    }
    __syncthreads();
  }
#undef STAGE

  float bv[4];
#pragma unroll
  for (int j = 0; j < 4; ++j) bv[j] = bout[n0 + wn * 64 + j * 16 + r];

#pragma unroll
  for (int i = 0; i < 4; ++i)
#pragma unroll
    for (int q = 0; q < 4; ++q) {
      const int row = m0 + wm * 64 + i * 16 + kg * 4 + q;
      float v = 0.0f;
#pragma unroll
      for (int j = 0; j < 4; ++j) {
        float e = __expf(acc[i][j][q] + bv[j]);
        out[(size_t)row * VOCAB + n0 + wn * 64 + j * 16 + r] = e;
        v += e;
      }
#pragma unroll
      for (int msk = 1; msk < 16; msk <<= 1) v += __shfl_xor(v, msk, 64);
      if (r == 0) atomicAdd(&rowsum[row], v);
    }
}

// Kernel 5: out *= 1/rowsum[row]. 4 blocks per row.
__global__ __launch_bounds__(256) void scale_kernel(
    float* __restrict__ out, const float* __restrict__ rowsum)
{
  const int row = blockIdx.x >> 2;       // 0..2047
  const int seg = blockIdx.x & 3;        // 4 segments of 2000 float4
  const float s = 1.0f / rowsum[row];
  float4* o4 = (float4*)(out + (size_t)row * VOCAB) + seg * 2000;
  for (int i = threadIdx.x; i < 2000; i += 256) {
    float4 v = o4[i];
    v.x *= s; v.y *= s; v.z *= s; v.w *= s;
    o4[i] = v;
  }
}

// ---------------------------------------------------------------------------
// Host launcher
// ---------------------------------------------------------------------------
extern "C" void kernel_launch(void* const* d_in, const int* in_sizes, int n_in,
                              void* d_out, int out_size, void* d_ws, size_t ws_size,
                              hipStream_t stream) {
  (void)in_sizes; (void)n_in; (void)out_size; (void)ws_size;

  const int*   x       = (const int*)d_in[0];
  const int*   y       = (const int*)d_in[1];
  const float* enc_emb = (const float*)d_in[2];
  const float* enc_Wk  = (const float*)d_in[3];
  const float* enc_Wr  = (const float*)d_in[4];
  const float* enc_b   = (const float*)d_in[5];
  const float* dec_emb = (const float*)d_in[6];
  const float* dec_Wk  = (const float*)d_in[7];
  const float* dec_Wr  = (const float*)d_in[8];
  const float* dec_b   = (const float*)d_in[9];
  const float* Wout    = (const float*)d_in[10];
  const float* bout    = (const float*)d_in[11];
  float* out = (float*)d_out;
  char*  ws  = (char*)d_ws;

  // workspace layout (bytes); rowsum+fmb contiguous -> ONE memset
  size_t off = 0;
  float* xz_enc = (float*)(ws + off); off += (size_t)BB * LS * G4 * 4;      // 16 MB
  float* xz_dec = (float*)(ws + off); off += (size_t)BB * LT * G4 * 4;      //  8 MB
  float* Henc   = (float*)(ws + off); off += (size_t)BB * LS * HID * 4;     //  4 MB
  float* S      = (float*)(ws + off); off += (size_t)BB * LT * HID * 4;     //  2 MB
  __hip_bfloat16* featB = (__hip_bfloat16*)(ws + off);
  off += (size_t)BB * LT * 2 * HID * 2;                                     //  2 MB
  ushort_t* WoutT = (ushort_t*)(ws + off); off += (size_t)VOCAB * 512 * 2;  // 32 MB
  float* c_fin  = (float*)(ws + off); off += (size_t)BB * HID * 4;
  size_t zero_base = off;
  float* rowsum = (float*)(ws + off); off += (size_t)BB * LT * 4;           //  8 KB
  i32x4* fmb    = (i32x4*)(ws + off); off += (size_t)BB * 2 * 128 * 16;     // 64 KB
  size_t zero_len = off - zero_base;

  hipMemsetAsync(ws + zero_base, 0, zero_len, stream);

  // input projections (enc + dec in one launch)
  embed_proj_kernel<<<192, 256, 0, stream>>>(
      x, y, enc_emb, enc_Wk, enc_b, dec_emb, dec_Wk, dec_b, xz_enc, xz_dec);

  // encoder LSTM (h0=c0=0): 128 WGs x 512 threads
  lstm_kernel<<<NSL * BB, 512, LSTM_POOL, stream>>>(
      xz_enc, enc_Wr, nullptr, 0, nullptr, Henc, c_fin, fmb, 0, LS);

  // decoder LSTM (h0 = enc final h rows inside Henc, c0 = c_fin)
  lstm_kernel<<<NSL * BB, 512, LSTM_POOL, stream>>>(
      xz_dec, dec_Wr, Henc + (size_t)(LS - 1) * HID, LS * HID, c_fin,
      S, nullptr, fmb, 1, LT);

  // attention (first) + prepack in one launch
  mid_kernel<<<4000 + BB * LT, 256, 0, stream>>>(
      Wout, WoutT, Henc, S, (__hip_bfloat16*)featB);

  // GEMM + exp (unnormalized) + rowsum; then scale
  proj_exp_kernel<<<16 * 250, 256, 0, stream>>>(
      (const ushort_t*)featB, WoutT, bout, rowsum, out);
  scale_kernel<<<4 * BB * LT, 256, 0, stream>>>(out, rowsum);
}

// Round 17
// 1030.828 us; speedup vs baseline: 1.0308x; 1.0226x over previous
//
#include <hip/hip_runtime.h>
#include <hip/hip_bf16.h>
#include <math.h>

// Problem constants
#define BB    16
#define LS    256
#define LT    128
#define EMB   128
#define HID   256
#define G4    1024      // 4*HID
#define VOCAB 32000

// LSTM slicing: 8 slice-WGs per batch, 512 threads each. (R10/R14-proven)
#define NSL   8
#define XROWS 112      // LDS-staged xz steps per burst (56 KB)
#define LSTM_POOL (4096 + XROWS * 128 * 4)   // 61440 B

typedef __attribute__((ext_vector_type(8))) short bf16x8;
typedef __attribute__((ext_vector_type(4))) float f32x4;
typedef __attribute__((ext_vector_type(4))) int   i32x4;
typedef unsigned short ushort_t;
typedef unsigned int uint_t;

__device__ inline float sigf(float x)      { return 1.0f / (1.0f + __expf(-x)); }
__device__ inline float tanhfast(float x)  { return 1.0f - 2.0f / (1.0f + __expf(2.0f * x)); }
__device__ inline ushort_t bf16_rne(float f) {
  __hip_bfloat16 h = __float2bfloat16(f);
  return *(ushort_t*)&h;
}

// ---------------------------------------------------------------------------
// Kernel 1: xz = emb[idx] @ Wk + b for BOTH enc and dec (one launch).
// ---------------------------------------------------------------------------
__global__ __launch_bounds__(256) void embed_proj_kernel(
    const int* __restrict__ x, const int* __restrict__ y,
    const float* __restrict__ eemb, const float* __restrict__ eWk,
    const float* __restrict__ eb,
    const float* __restrict__ demb, const float* __restrict__ dWk,
    const float* __restrict__ db,
    float* __restrict__ xze, float* __restrict__ xzd)
{
  const bool enc = blockIdx.x < 128;
  const int* idx = enc ? x : y;
  const float* emb = enc ? eemb : demb;
  const float* Wk  = enc ? eWk  : dWk;
  const float* bias= enc ? eb   : db;
  float* xz        = enc ? xze  : xzd;
  const int row0 = (enc ? blockIdx.x : blockIdx.x - 128) * 32;

  __shared__ float e[32][EMB];    // 16 KB
  const int tid = threadIdx.x;

  for (int i = tid; i < 32 * EMB; i += 256) {
    int r = i >> 7, k = i & 127;
    int token = idx[row0 + r];
    e[r][k] = emb[(size_t)token * EMB + k];
  }
  __syncthreads();

  float acc[4][32];
#pragma unroll
  for (int q = 0; q < 4; ++q)
#pragma unroll
    for (int r = 0; r < 32; ++r) acc[q][r] = 0.0f;

  for (int k = 0; k < EMB; ++k) {
    float w0 = Wk[(size_t)k * G4 + 0 * 256 + tid];
    float w1 = Wk[(size_t)k * G4 + 1 * 256 + tid];
    float w2 = Wk[(size_t)k * G4 + 2 * 256 + tid];
    float w3 = Wk[(size_t)k * G4 + 3 * 256 + tid];
#pragma unroll
    for (int r = 0; r < 32; ++r) {
      float ev = e[r][k];
      acc[0][r] = fmaf(ev, w0, acc[0][r]);
      acc[1][r] = fmaf(ev, w1, acc[1][r]);
      acc[2][r] = fmaf(ev, w2, acc[2][r]);
      acc[3][r] = fmaf(ev, w3, acc[3][r]);
    }
  }
#pragma unroll
  for (int q = 0; q < 4; ++q) {
    float bb = bias[q * 256 + tid];
#pragma unroll
    for (int r = 0; r < 32; ++r)
      xz[(size_t)(row0 + r) * G4 + q * 256 + tid] = acc[q][r] + bb;
  }
}

// ---------------------------------------------------------------------------
// Kernel 2: LSTM recurrence, 8 slice-WGs per batch (128 WGs x 512 threads).
// R14-EXACT (measured floor): far-only (sc0 sc1) checksummed mailbox chunks
// {h0,h1,h0^h1^stamp,0}, stamp=(t+1)|(kid<<20), slot parity t&1, pacing
// barrier after stores, SINGLE far probe per poll iteration (all 512
// threads), 32-lane pointwise. Sync ledger — all rejected by measurement:
// near-L2 probes (R7/R9), sticky-near (R8 hang), no-barrier (R7), 2-deep
// pipelined poll (R12), batch-pairing (R13), reduced poll fan-out + LDS
// broadcast (R15). This structure is the protocol floor.
// ---------------------------------------------------------------------------
__device__ __forceinline__ void lstm_body(
    char* pool, int bid,
    const float* __restrict__ xz, const float* __restrict__ Wr,
    const float* __restrict__ h0, int h0_stride,
    const float* __restrict__ cinit,
    float* __restrict__ Hout, float* __restrict__ c_fin,
    i32x4* __restrict__ fmb, int kid, int T)
{
  float (*part)[4][128] = (float (*)[4][128])pool;         // 4 KB (x2 parity)
  float (*xbuf)[128]    = (float (*)[128])(pool + 4096);   // 56 KB

  const int b    = bid & (BB - 1);
  const int s    = bid >> 4;
  const int tid  = threadIdx.x;
  const int lane = tid & 63;
  const int quarter = tid >> 7;        // 0..3 : h-dim range quarter*64..+64
  const int col  = tid & 127;          // gate col within slice
  const int gate = col >> 5, u = col & 31;

  // weight column slice in registers
  float w_r[64];
  {
    const float* wp = Wr + (size_t)(quarter * 64) * G4 + gate * 256 + s * 32 + u;
#pragma unroll
    for (int j = 0; j < 64; ++j) w_r[j] = wp[(size_t)j * G4];
  }

  const int i0 = quarter * 64 + lane;
  float hv = 0.0f;
  if (h0) hv = h0[(size_t)b * h0_stride + i0];

  // pointwise: 32 lanes, one unit each; lanes 0..15 even units, 16..31 odd.
  const int pu = (tid < 16) ? (2 * tid) : (2 * (tid - 16) + 1);
  float cs = 0.0f;
  if (tid < 32 && cinit) cs = cinit[b * HID + s * 32 + pu];

  const int c0i = i0 >> 1;   // mailbox chunk holding h[i0]
  const int sel = i0 & 1;

  int tp = XROWS;
  for (int t = 0; t < T; ++t, ++tp) {
    // ---- periodic xz burst into LDS ----
    if (tp >= XROWS) {
      __syncthreads();               // all readers of old xbuf are done
      tp = 0;
      for (int tt = quarter; tt < XROWS; tt += 4) {
        int ts = t + tt;
        if (ts < T)
          xbuf[tt][col] = xz[((size_t)b * T + ts) * G4 + gate * 256 + s * 32 + u];
      }
    }

    // ---- partial dot over this quarter's 64 h values (4 chains) ----
    float a0 = 0.0f, a1 = 0.0f, a2 = 0.0f, a3 = 0.0f;
#pragma unroll
    for (int j = 0; j < 64; j += 4) {
      a0 = fmaf(__int_as_float(__builtin_amdgcn_readlane(__float_as_int(hv), j + 0)), w_r[j + 0], a0);
      a1 = fmaf(__int_as_float(__builtin_amdgcn_readlane(__float_as_int(hv), j + 1)), w_r[j + 1], a1);
      a2 = fmaf(__int_as_float(__builtin_amdgcn_readlane(__float_as_int(hv), j + 2)), w_r[j + 2], a2);
      a3 = fmaf(__int_as_float(__builtin_amdgcn_readlane(__float_as_int(hv), j + 3)), w_r[j + 3], a3);
    }
    part[t & 1][quarter][col] = (a0 + a1) + (a2 + a3);
    __syncthreads();                 // part ready

    const int stamp = (t + 1) | (kid << 20);
    const size_t slot = (size_t)(b * 2 + (t & 1)) * 128;

    // ---- pointwise (lanes 0..31, one unit each); publish from 0..15 ----
    if (tid < 32) {
      const float (*pp)[128] = part[t & 1];
      float zi = pp[0][pu]      + pp[1][pu]      + pp[2][pu]      + pp[3][pu]
               + xbuf[tp][pu];
      float zf = pp[0][32 + pu] + pp[1][32 + pu] + pp[2][32 + pu] + pp[3][32 + pu]
               + xbuf[tp][32 + pu];
      float zg = pp[0][64 + pu] + pp[1][64 + pu] + pp[2][64 + pu] + pp[3][64 + pu]
               + xbuf[tp][64 + pu];
      float zo = pp[0][96 + pu] + pp[1][96 + pu] + pp[2][96 + pu] + pp[3][96 + pu]
               + xbuf[tp][96 + pu];

      cs = fmaf(sigf(zf), cs, sigf(zi) * tanhfast(zg));
      float h = sigf(zo) * tanhfast(cs);

      float hodd = __shfl_down(h, 16, 64);   // lanes 0..15 <- lanes 16..31

      if (tid < 16) {
        const int ua = 2 * tid;
        *(float2*)&Hout[((size_t)b * T + t) * HID + s * 32 + ua] =
            make_float2(h, hodd);

        i32x4 ch;
        ch.x = __float_as_int(h);
        ch.y = __float_as_int(hodd);
        ch.z = ch.x ^ ch.y ^ stamp;
        ch.w = 0;
        const i32x4* fd = fmb + slot + s * 16 + tid;
        asm volatile("global_store_dwordx4 %0, %1, off sc0 sc1"
                     :: "v"(fd), "v"(ch) : "memory");
      }
    }
    __syncthreads();   // pacing: stores drained (vmcnt in barrier) before polls

    // ---- poll h(t): far-only single probe (R14-proven floor) ----
    if (t + 1 < T) {
      const i32x4* fp = fmb + slot + c0i;
      i32x4 v;
      for (;;) {
        asm volatile("global_load_dwordx4 %0, %1, off sc0 sc1\n\t"
                     "s_waitcnt vmcnt(0)"
                     : "=&v"(v) : "v"(fp) : "memory");
        if (v.z == (v.x ^ v.y ^ stamp)) break;
      }
      hv = __int_as_float(sel ? v.y : v.x);
    }
  }
  if (c_fin && tid < 32) c_fin[b * HID + s * 32 + pu] = cs;
}

__global__ __launch_bounds__(512, 1) void lstm_kernel(
    const float* __restrict__ xz, const float* __restrict__ Wr,
    const float* __restrict__ h0, int h0_stride,
    const float* __restrict__ cinit,
    float* __restrict__ Hout, float* __restrict__ c_fin,
    i32x4* __restrict__ fmb, int kid, int T)
{
  extern __shared__ char pool[];
  lstm_body(pool, blockIdx.x, xz, Wr, h0, h0_stride, cinit,
            Hout, c_fin, fmb, kid, T);
}

// ---------------------------------------------------------------------------
// Kernel 3 (merged): blocks [0,4000): prepack WoutT[n][k] = bf16(Wout[k][n]);
// blocks [4000,6048): attention + bf16 feat pack.  (R14-proven order)
// ---------------------------------------------------------------------------
__global__ __launch_bounds__(256) void mid_kernel(
    const float* __restrict__ W, ushort_t* __restrict__ WT,
    const float* __restrict__ Henc, const float* __restrict__ S,
    __hip_bfloat16* __restrict__ featB)
{
  const int tid = threadIdx.x;

  if (blockIdx.x < 4000) {
    // ---------------- prepack ----------------
    __shared__ float tile[64][65];
    const int nt = blockIdx.x % 500;
    const int kt = blockIdx.x / 500;
    const int n0 = nt * 64, k0 = kt * 64;
    const int r = tid >> 6, c = tid & 63;

#pragma unroll
    for (int q = 0; q < 16; ++q) {
      int kk = q * 4 + r;
      tile[kk][c] = W[(size_t)(k0 + kk) * VOCAB + n0 + c];
    }
    __syncthreads();

    const int nl = tid >> 2;             // 0..63 output row
    const int seg = (tid & 3) * 16;      // 16 k per thread
    uint_t o[8];
#pragma unroll
    for (int j = 0; j < 8; ++j) {
      uint_t lo = bf16_rne(tile[seg + 2 * j][nl]);
      uint_t hi = bf16_rne(tile[seg + 2 * j + 1][nl]);
      o[j] = lo | (hi << 16);
    }
    ushort_t* dst = WT + (size_t)(n0 + nl) * 512 + k0 + seg;
    ((uint4*)dst)[0] = make_uint4(o[0], o[1], o[2], o[3]);
    ((uint4*)dst)[1] = make_uint4(o[4], o[5], o[6], o[7]);
  } else {
    // ---------------- attention ----------------
    __shared__ float srow[HID];
    __shared__ float p[LS];
    __shared__ float sm[LS];

    const int m = blockIdx.x - 4000;   // b*LT + t
    const int b = m >> 7, t = m & (LT - 1);

    const float* s_ = (t == 0) ? (Henc + ((size_t)b * LS + (LS - 1)) * HID)
                               : (S + (size_t)(m - 1) * HID);
    srow[tid] = s_[tid];
    __syncthreads();

    const float4* h4 = (const float4*)(Henc + ((size_t)b * LS + tid) * HID);
    const float4* s4 = (const float4*)srow;
    float sc = 0.0f;
#pragma unroll 8
    for (int k = 0; k < HID / 4; ++k) {
      float4 a = h4[k], q = s4[k];
      sc += a.x * q.x + a.y * q.y + a.z * q.z + a.w * q.w;
    }
    sm[tid] = sc;
    __syncthreads();
    for (int st = 128; st > 0; st >>= 1) {
      if (tid < st) sm[tid] = fmaxf(sm[tid], sm[tid + st]);
      __syncthreads();
    }
    float mx = sm[0];
    __syncthreads();
    float e = __expf(sc - mx);
    p[tid] = e;
    sm[tid] = e;
    __syncthreads();
    for (int st = 128; st > 0; st >>= 1) {
      if (tid < st) sm[tid] += sm[tid + st];
      __syncthreads();
    }
    float inv = 1.0f / sm[0];

    float a_d = 0.0f;
#pragma unroll 4
    for (int s2 = 0; s2 < LS; ++s2)
      a_d = fmaf(p[s2], Henc[((size_t)b * LS + s2) * HID + tid], a_d);
    a_d *= inv;

    featB[(size_t)m * (2 * HID) + tid]       = __float2bfloat16(S[(size_t)m * HID + tid]);
    featB[(size_t)m * (2 * HID) + HID + tid] = __float2bfloat16(a_d);
  }
}

// ---------------------------------------------------------------------------
// Kernel 4: logits GEMM, 128x128 tile, BK=64, double-buffered LDS,
// global_load_lds width=16 staging (R12-verified). Linear LDS dest +
// source-side XOR swizzle (rule-21 both-sides involution).
// Epilogue: E = exp(logit+bias) stored unnormalized + rowsum atomics.
// ---------------------------------------------------------------------------
__global__ __launch_bounds__(256) void proj_exp_kernel(
    const ushort_t* __restrict__ A, const ushort_t* __restrict__ BT,
    const float* __restrict__ bout, float* __restrict__ rowsum,
    float* __restrict__ out)
{
  __shared__ ushort_t Ab[2][128 * 64];   // 16 KB each
  __shared__ ushort_t Bb[2][128 * 64];

  const int bid = blockIdx.x;
  const int k2 = (bid & 7) * 500 + (bid >> 3);   // XCD-chunked
  const int mt = k2 & 15, nt = k2 >> 4;          // 16 x 250
  const int m0 = mt * 128, n0 = nt * 128;
  const int tid = threadIdx.x;
  const int wave = tid >> 6, lane = tid & 63;
  const int wm = wave >> 1, wn = wave & 1;
  const int r = lane & 15, kg = lane >> 4;

  const ushort_t* Ag = A + (size_t)m0 * 512;
  const ushort_t* Bg = BT + (size_t)n0 * 512;

  f32x4 acc[4][4];
#pragma unroll
  for (int i = 0; i < 4; ++i)
#pragma unroll
    for (int j = 0; j < 4; ++j) acc[i][j] = (f32x4){0.f, 0.f, 0.f, 0.f};

  // async global->LDS staging: linear LDS dest, swizzled global source
#define STAGE(kc, buf)                                                        \
  {                                                                           \
    _Pragma("unroll")                                                         \
    for (int q = 0; q < 4; ++q) {                                             \
      int L = q * 256 + tid;                                                  \
      int row_ = L >> 3, seg_ = L & 7;                                        \
      int sseg_ = seg_ ^ (row_ & 7);                                          \
      int wbase = (q * 256 + (tid & ~63)) * 8;  /* wave-uniform ushort idx */ \
      __builtin_amdgcn_global_load_lds(                                       \
          (const __attribute__((address_space(1))) unsigned int*)             \
              (Ag + (size_t)row_ * 512 + (kc) * 64 + sseg_ * 8),              \
          (__attribute__((address_space(3))) unsigned int*)&Ab[buf][wbase],   \
          16, 0, 0);                                                          \
      __builtin_amdgcn_global_load_lds(                                       \
          (const __attribute__((address_space(1))) unsigned int*)             \
              (Bg + (size_t)row_ * 512 + (kc) * 64 + sseg_ * 8),              \
          (__attribute__((address_space(3))) unsigned int*)&Bb[buf][wbase],   \
          16, 0, 0);                                                          \
    }                                                                         \
  }

  STAGE(0, 0);
  __syncthreads();

  for (int kc = 0; kc < 8; ++kc) {
    const int cur = kc & 1;
    if (kc < 7) STAGE(kc + 1, cur ^ 1);
#pragma unroll
    for (int ks = 0; ks < 2; ++ks) {
      bf16x8 a[4], b[4];
      const int seg = ks * 4 + kg;
#pragma unroll
      for (int i = 0; i < 4; ++i) {
        int row = wm * 64 + i * 16 + r;
        a[i] = *(const bf16x8*)&Ab[cur][row * 64 + ((seg ^ (row & 7)) << 3)];
      }
#pragma unroll
      for (int j = 0; j < 4; ++j) {
        int row = wn * 64 + j * 16 + r;
        b[j] = *(const bf16x8*)&Bb[cur][row * 64 + ((seg ^ (row & 7)) << 3)];
      }
#pragma unroll
      for (int i = 0; i < 4; ++i)
#pragma unroll
        for (int j = 0; j < 4; ++j)
          acc[i][j] = __builtin_amdgcn_mfma_f32_16x16x32_bf16(a[i], b[j], acc[i][j], 0, 0, 0);
    }
    __syncthreads();
  }
#undef STAGE

  float bv[4];
#pragma unroll
  for (int j = 0; j < 4; ++j) bv[j] = bout[n0 + wn * 64 + j * 16 + r];

#pragma unroll
  for (int i = 0; i < 4; ++i)
#pragma unroll
    for (int q = 0; q < 4; ++q) {
      const int row = m0 + wm * 64 + i * 16 + kg * 4 + q;
      float v = 0.0f;
#pragma unroll
      for (int j = 0; j < 4; ++j) {
        float e = __expf(acc[i][j][q] + bv[j]);
        out[(size_t)row * VOCAB + n0 + wn * 64 + j * 16 + r] = e;
        v += e;
      }
#pragma unroll
      for (int msk = 1; msk < 16; msk <<= 1) v += __shfl_xor(v, msk, 64);
      if (r == 0) atomicAdd(&rowsum[row], v);
    }
}

// Kernel 5: out *= 1/rowsum[row]. 4 blocks per row.
__global__ __launch_bounds__(256) void scale_kernel(
    float* __restrict__ out, const float* __restrict__ rowsum)
{
  const int row = blockIdx.x >> 2;       // 0..2047
  const int seg = blockIdx.x & 3;        // 4 segments of 2000 float4
  const float s = 1.0f / rowsum[row];
  float4* o4 = (float4*)(out + (size_t)row * VOCAB) + seg * 2000;
  for (int i = threadIdx.x; i < 2000; i += 256) {
    float4 v = o4[i];
    v.x *= s; v.y *= s; v.z *= s; v.w *= s;
    o4[i] = v;
  }
}

// ---------------------------------------------------------------------------
// Host launcher
// ---------------------------------------------------------------------------
extern "C" void kernel_launch(void* const* d_in, const int* in_sizes, int n_in,
                              void* d_out, int out_size, void* d_ws, size_t ws_size,
                              hipStream_t stream) {
  (void)in_sizes; (void)n_in; (void)out_size; (void)ws_size;

  const int*   x       = (const int*)d_in[0];
  const int*   y       = (const int*)d_in[1];
  const float* enc_emb = (const float*)d_in[2];
  const float* enc_Wk  = (const float*)d_in[3];
  const float* enc_Wr  = (const float*)d_in[4];
  const float* enc_b   = (const float*)d_in[5];
  const float* dec_emb = (const float*)d_in[6];
  const float* dec_Wk  = (const float*)d_in[7];
  const float* dec_Wr  = (const float*)d_in[8];
  const float* dec_b   = (const float*)d_in[9];
  const float* Wout    = (const float*)d_in[10];
  const float* bout    = (const float*)d_in[11];
  float* out = (float*)d_out;
  char*  ws  = (char*)d_ws;

  // workspace layout (bytes); rowsum+fmb contiguous -> ONE memset
  size_t off = 0;
  float* xz_enc = (float*)(ws + off); off += (size_t)BB * LS * G4 * 4;      // 16 MB
  float* xz_dec = (float*)(ws + off); off += (size_t)BB * LT * G4 * 4;      //  8 MB
  float* Henc   = (float*)(ws + off); off += (size_t)BB * LS * HID * 4;     //  4 MB
  float* S      = (float*)(ws + off); off += (size_t)BB * LT * HID * 4;     //  2 MB
  __hip_bfloat16* featB = (__hip_bfloat16*)(ws + off);
  off += (size_t)BB * LT * 2 * HID * 2;                                     //  2 MB
  ushort_t* WoutT = (ushort_t*)(ws + off); off += (size_t)VOCAB * 512 * 2;  // 32 MB
  float* c_fin  = (float*)(ws + off); off += (size_t)BB * HID * 4;
  size_t zero_base = off;
  float* rowsum = (float*)(ws + off); off += (size_t)BB * LT * 4;           //  8 KB
  i32x4* fmb    = (i32x4*)(ws + off); off += (size_t)BB * 2 * 128 * 16;     // 64 KB
  size_t zero_len = off - zero_base;

  hipMemsetAsync(ws + zero_base, 0, zero_len, stream);

  // input projections (enc + dec in one launch)
  embed_proj_kernel<<<192, 256, 0, stream>>>(
      x, y, enc_emb, enc_Wk, enc_b, dec_emb, dec_Wk, dec_b, xz_enc, xz_dec);

  // encoder LSTM (h0=c0=0): 128 WGs x 512 threads
  lstm_kernel<<<NSL * BB, 512, LSTM_POOL, stream>>>(
      xz_enc, enc_Wr, nullptr, 0, nullptr, Henc, c_fin, fmb, 0, LS);

  // decoder LSTM (h0 = enc final h rows inside Henc, c0 = c_fin)
  lstm_kernel<<<NSL * BB, 512, LSTM_POOL, stream>>>(
      xz_dec, dec_Wr, Henc + (size_t)(LS - 1) * HID, LS * HID, c_fin,
      S, nullptr, fmb, 1, LT);

  // prepack + attention in one launch
  mid_kernel<<<4000 + BB * LT, 256, 0, stream>>>(
      Wout, WoutT, Henc, S, (__hip_bfloat16*)featB);

  // GEMM + exp (unnormalized) + rowsum; then scale
  proj_exp_kernel<<<16 * 250, 256, 0, stream>>>(
      (const ushort_t*)featB, WoutT, bout, rowsum, out);
  scale_kernel<<<4 * BB * LT, 256, 0, stream>>>(out, rowsum);
}